// Round 1
// baseline (121.744 us; speedup 1.0000x reference)
//
#include <hip/hip_runtime.h>
#include <math.h>

// Problem constants (match reference)
#define BATCH 16384
#define NN    1024
#define NI    128
#define NO    64
#define REFR  0.9f

typedef float  f32x4  __attribute__((ext_vector_type(4)));
typedef __bf16 bf16x8 __attribute__((ext_vector_type(8)));

// ---------------------------------------------------------------------------
// Kernel 1: pack W[:, 960:1024] into bf16 B-fragments for mfma_f32_16x16x32_bf16
// Fragment order: frag[(kc*4 + t)*64 + lane][j] = bf16(W[kc*32 + (lane>>4)*8 + j][960 + t*16 + (lane&15)])
// so the main kernel's per-lane 16B load is fully coalesced.
// ---------------------------------------------------------------------------
__global__ __launch_bounds__(256) void pack_w_kernel(const float* __restrict__ W,
                                                     __bf16* __restrict__ wsB) {
    int idx = blockIdx.x * 256 + threadIdx.x;   // 0 .. 65535
    int j  = idx & 7;
    int l  = (idx >> 3) & 63;
    int tn = (idx >> 9) & 3;
    int kc = idx >> 11;
    int k  = kc * 32 + (l >> 4) * 8 + j;
    int n  = tn * 16 + (l & 15);
    wsB[idx] = (__bf16)W[(size_t)k * NN + (NN - NO) + n];
}

__device__ inline float activate(float x, int id) {
    if (id == 0) return fmaxf(x, 0.0f);
    if (id == 1) return tanhf(x);
    if (id == 2) return 1.0f / (1.0f + __expf(-x));
    return x;
}

// ---------------------------------------------------------------------------
// Kernel 2: fused refractory/input-assign + GEMM (M=16384, N=64, K=1024) + bias
// + heterogeneous activation, writing only the output slice [B, 64].
// One wave handles a 16-row M-tile and all 64 output columns (4 C-frags).
// ---------------------------------------------------------------------------
__global__ __launch_bounds__(256) void fused_rnn_kernel(
    const float* __restrict__ prev,
    const float* __restrict__ inp,
    const __bf16* __restrict__ wsB,
    const float* __restrict__ bias,
    const int*  __restrict__ act,
    float* __restrict__ out)
{
    const int lane = threadIdx.x & 63;
    const int wv   = threadIdx.x >> 6;
    const int m    = lane & 15;   // A-row within tile / D-col within tile
    const int q    = lane >> 4;   // quad
    const int row0 = blockIdx.x * 64 + wv * 16;
    const int rowA = row0 + m;

    const float* prow = prev + (size_t)rowA * NN;
    const float* irow = inp  + (size_t)rowA * NI;
    const bf16x8* Bf  = (const bf16x8*)wsB;

    f32x4 acc[4];
    acc[0] = (f32x4){0.f, 0.f, 0.f, 0.f};
    acc[1] = acc[0]; acc[2] = acc[0]; acc[3] = acc[0];

    const int qo = q * 8;

    // One K-chunk (32 wide): load A fragment from `src` at column kc*32, scale,
    // convert to bf16, then 4 MFMAs against the packed B-fragments.
#define K_STEP(kc, srcRow, scale)                                              \
    {                                                                          \
        const float4* p = (const float4*)((srcRow) + (kc) * 32 + qo);          \
        float4 f0 = p[0];                                                      \
        float4 f1 = p[1];                                                      \
        bf16x8 a;                                                              \
        a[0] = (__bf16)(f0.x * (scale)); a[1] = (__bf16)(f0.y * (scale));      \
        a[2] = (__bf16)(f0.z * (scale)); a[3] = (__bf16)(f0.w * (scale));      \
        a[4] = (__bf16)(f1.x * (scale)); a[5] = (__bf16)(f1.y * (scale));      \
        a[6] = (__bf16)(f1.z * (scale)); a[7] = (__bf16)(f1.w * (scale));      \
        const bf16x8* bp = Bf + (size_t)(kc) * 256 + lane;                     \
        acc[0] = __builtin_amdgcn_mfma_f32_16x16x32_bf16(a, bp[0],   acc[0], 0, 0, 0); \
        acc[1] = __builtin_amdgcn_mfma_f32_16x16x32_bf16(a, bp[64],  acc[1], 0, 0, 0); \
        acc[2] = __builtin_amdgcn_mfma_f32_16x16x32_bf16(a, bp[128], acc[2], 0, 0, 0); \
        acc[3] = __builtin_amdgcn_mfma_f32_16x16x32_bf16(a, bp[192], acc[3], 0, 0, 0); \
    }

    // k in [0,128): states = input_values (columns map 1:1), scale 1
#pragma unroll
    for (int kc = 0; kc < 4; ++kc) K_STEP(kc, irow, 1.0f)

    // k in [128,960): states = prev * 0.9  (region boundaries are 32-aligned)
#pragma unroll 4
    for (int kc = 4; kc < 30; ++kc) K_STEP(kc, prow, REFR)

    // k in [960,1024): states = prev (output neurons keep raw state)
#pragma unroll
    for (int kc = 30; kc < 32; ++kc) K_STEP(kc, prow, 1.0f)

#undef K_STEP

    // Epilogue: D layout col = lane&15, row = q*4 + reg  [measured m89]
    const float* bo = bias + (NN - NO);
    const int*   ao = act  + (NN - NO);
#pragma unroll
    for (int t = 0; t < 4; ++t) {
        const int col = t * 16 + m;
        const float bb = bo[col];
        const int   id = ao[col];
#pragma unroll
        for (int r = 0; r < 4; ++r) {
            const int rr = row0 + q * 4 + r;
            out[(size_t)rr * NO + col] = activate(acc[t][r] + bb, id);
        }
    }
}

extern "C" void kernel_launch(void* const* d_in, const int* in_sizes, int n_in,
                              void* d_out, int out_size, void* d_ws, size_t ws_size,
                              hipStream_t stream) {
    const float* prev = (const float*)d_in[0];   // [B, N] fp32
    const float* inp  = (const float*)d_in[1];   // [B, I] fp32
    const float* W    = (const float*)d_in[2];   // [N, N] fp32
    const float* bias = (const float*)d_in[3];   // [N]    fp32
    const int*   act  = (const int*)  d_in[4];   // [N]    int32
    float* out = (float*)d_out;                  // [B, O] fp32
    __bf16* wsB = (__bf16*)d_ws;                 // 65536 bf16 = 128 KB

    // Pack W slice into MFMA B-fragment order (ws is re-poisoned each call,
    // so this must run every launch; it's ~0.4 MB of traffic).
    pack_w_kernel<<<256, 256, 0, stream>>>(W, wsB);

    // Main fused kernel: 256 blocks x 256 threads; each wave = 16 rows.
    fused_rnn_kernel<<<BATCH / 64, 256, 0, stream>>>(prev, inp, wsB, bias, act, out);
}

// Round 2
// 117.653 us; speedup vs baseline: 1.0348x; 1.0348x over previous
//
#include <hip/hip_runtime.h>
#include <math.h>

// Problem constants (match reference)
#define BATCH 16384
#define NN    1024
#define NI    128
#define NO    64
#define REFR  0.9f

typedef float  f32x4  __attribute__((ext_vector_type(4)));
typedef __bf16 bf16x8 __attribute__((ext_vector_type(8)));

// ---------------------------------------------------------------------------
// Kernel 1: pack W[:, 960:1024] into bf16 B-fragments for mfma_f32_16x16x32_bf16
// frag[(kc*4 + t)*64 + lane][j] = bf16(W[kc*32 + (lane>>4)*8 + j][960 + t*16 + (lane&15)])
// so the main kernel's per-lane 16B B-load is fully coalesced (L2-resident).
// ---------------------------------------------------------------------------
__global__ __launch_bounds__(256) void pack_w_kernel(const float* __restrict__ W,
                                                     __bf16* __restrict__ wsB) {
    int idx = blockIdx.x * 256 + threadIdx.x;   // 0 .. 65535
    int j  = idx & 7;
    int l  = (idx >> 3) & 63;
    int tn = (idx >> 9) & 3;
    int kc = idx >> 11;
    int k  = kc * 32 + (l >> 4) * 8 + j;
    int n  = tn * 16 + (l & 15);
    wsB[idx] = (__bf16)W[(size_t)k * NN + (NN - NO) + n];
}

__device__ inline float activate(float x, int id) {
    if (id == 0) return fmaxf(x, 0.0f);
    if (id == 1) return tanhf(x);
    if (id == 2) return 1.0f / (1.0f + __expf(-x));
    return x;
}

// ---------------------------------------------------------------------------
// Kernel 2: fused refractory/input-assign + GEMM (M=16384, N=64, K=1024) + bias
// + heterogeneous activation. K-split x4: one block (4 waves) per 16-row tile;
// wave w handles K-chunks [8w, 8w+8); partials combined via LDS.
// 1024 blocks -> 4 blocks/CU -> 4 waves/SIMD (vs 1 before: latency hiding).
// ---------------------------------------------------------------------------
__global__ __launch_bounds__(256, 4) void fused_rnn_kernel(
    const float* __restrict__ prev,
    const float* __restrict__ inp,
    const __bf16* __restrict__ wsB,
    const float* __restrict__ bias,
    const int*  __restrict__ act,
    float* __restrict__ out)
{
    const int lane = threadIdx.x & 63;
    const int wv   = threadIdx.x >> 6;   // K-split index, 0..3
    const int m    = lane & 15;          // A-row within tile / D-col within frag
    const int q    = lane >> 4;          // quad
    const int tile = blockIdx.x;         // 16-row M-tile
    const int row0 = tile * 16;
    const int rowA = row0 + m;

    const float* prow = prev + (size_t)rowA * NN;
    const float* irow = inp  + (size_t)rowA * NI;
    const bf16x8* Bf  = (const bf16x8*)wsB;

    f32x4 acc[4];
    acc[0] = (f32x4){0.f, 0.f, 0.f, 0.f};
    acc[1] = acc[0]; acc[2] = acc[0]; acc[3] = acc[0];

    const int qo = q * 8;

    // 8 K-chunks for this wave, fully unrolled -> 16 independent A-loads in flight.
#pragma unroll
    for (int i = 0; i < 8; ++i) {
        const int kc = wv * 8 + i;
        // Region select (wave-uniform scalar branch): cols [0,128) = input_values,
        // [128,960) = prev*0.9, [960,1024) = prev. Boundaries are 32-aligned.
        const float* srcRow = (kc < 4) ? irow : prow;
        const float  scale  = (kc >= 4 && kc < 30) ? REFR : 1.0f;

        const float4* p = (const float4*)(srcRow + kc * 32 + qo);
        float4 f0 = p[0];
        float4 f1 = p[1];
        bf16x8 a;
        a[0] = (__bf16)(f0.x * scale); a[1] = (__bf16)(f0.y * scale);
        a[2] = (__bf16)(f0.z * scale); a[3] = (__bf16)(f0.w * scale);
        a[4] = (__bf16)(f1.x * scale); a[5] = (__bf16)(f1.y * scale);
        a[6] = (__bf16)(f1.z * scale); a[7] = (__bf16)(f1.w * scale);

        const bf16x8* bp = Bf + (size_t)kc * 256 + lane;
        acc[0] = __builtin_amdgcn_mfma_f32_16x16x32_bf16(a, bp[0],   acc[0], 0, 0, 0);
        acc[1] = __builtin_amdgcn_mfma_f32_16x16x32_bf16(a, bp[64],  acc[1], 0, 0, 0);
        acc[2] = __builtin_amdgcn_mfma_f32_16x16x32_bf16(a, bp[128], acc[2], 0, 0, 0);
        acc[3] = __builtin_amdgcn_mfma_f32_16x16x32_bf16(a, bp[192], acc[3], 0, 0, 0);
    }

    // ---- Cross-wave K-reduction via LDS ----
    // D layout: col = t*16 + m, row = q*4 + r  [measured m89]
    __shared__ float red[4][16][68];   // [wave][row][col] (+4 pad)
#pragma unroll
    for (int t = 0; t < 4; ++t) {
#pragma unroll
        for (int r = 0; r < 4; ++r) {
            red[wv][q * 4 + r][t * 16 + m] = acc[t][r];
        }
    }
    __syncthreads();

    // Each of the 256 threads produces one float4 of output: row = tid>>4,
    // cols [ (tid&15)*4, +4 ). Coalesced 16B global store.
    const int orow = threadIdx.x >> 4;
    const int oc   = (threadIdx.x & 15) * 4;

    f32x4 s;
    {
        const f32x4* p0 = (const f32x4*)&red[0][orow][oc];
        const f32x4* p1 = (const f32x4*)&red[1][orow][oc];
        const f32x4* p2 = (const f32x4*)&red[2][orow][oc];
        const f32x4* p3 = (const f32x4*)&red[3][orow][oc];
        s = *p0 + *p1 + *p2 + *p3;
    }

    const float* bo = bias + (NN - NO);
    const int*   ao = act  + (NN - NO);
    f32x4 o;
#pragma unroll
    for (int c = 0; c < 4; ++c) {
        o[c] = activate(s[c] + bo[oc + c], ao[oc + c]);
    }
    *(f32x4*)(out + (size_t)(row0 + orow) * NO + oc) = o;
}

extern "C" void kernel_launch(void* const* d_in, const int* in_sizes, int n_in,
                              void* d_out, int out_size, void* d_ws, size_t ws_size,
                              hipStream_t stream) {
    const float* prev = (const float*)d_in[0];   // [B, N] fp32
    const float* inp  = (const float*)d_in[1];   // [B, I] fp32
    const float* W    = (const float*)d_in[2];   // [N, N] fp32
    const float* bias = (const float*)d_in[3];   // [N]    fp32
    const int*   act  = (const int*)  d_in[4];   // [N]    int32
    float* out = (float*)d_out;                  // [B, O] fp32
    __bf16* wsB = (__bf16*)d_ws;                 // 65536 bf16 = 128 KB

    // Pack W slice into MFMA B-fragment order (ws is re-poisoned each call,
    // so this must run every launch; ~0.5 MB of traffic).
    pack_w_kernel<<<256, 256, 0, stream>>>(W, wsB);

    // Main fused kernel: one block per 16-row tile, K-split x4 inside the block.
    fused_rnn_kernel<<<BATCH / 16, 256, 0, stream>>>(prev, inp, wsB, bias, act, out);
}

// Round 3
// 114.288 us; speedup vs baseline: 1.0652x; 1.0294x over previous
//
#include <hip/hip_runtime.h>
#include <math.h>

// Problem constants (match reference)
#define BATCH 16384
#define NN    1024
#define NI    128
#define NO    64
#define REFR  0.9f

typedef float  f32x4  __attribute__((ext_vector_type(4)));
typedef __bf16 bf16x8 __attribute__((ext_vector_type(8)));

// ---------------------------------------------------------------------------
// Kernel 1: pack W[:, 960:1024] into bf16 B-fragments for mfma_f32_16x16x32_bf16,
// WITH the refractory scale folded in: rows k in [128,960) are pre-multiplied
// by 0.9 (scale is per-k, so scaling W is identical to scaling states).
// Thread map: k = idx>>6, n = idx&63  ->  64 lanes read 256 B contiguous per
// W row (coalesced); the 2 B frag writes scatter (stores don't stall).
// Frag layout (consumed by fused kernel): element j of frag[(kc*4+tn)*64 + l]
//   = W[kc*32 + (l>>4)*8 + j][960 + tn*16 + (l&15)]   [m89 B-layout]
// ---------------------------------------------------------------------------
__global__ __launch_bounds__(256) void pack_w_kernel(const float* __restrict__ W,
                                                     __bf16* __restrict__ wsB) {
    int idx = blockIdx.x * 256 + threadIdx.x;   // 0 .. 65535
    int k = idx >> 6;        // 0..1023
    int n = idx & 63;        // 0..63
    float v = W[(size_t)k * NN + (NN - NO) + n];
    int kc = k >> 5;
    if (kc >= 4 && kc < 30) v *= REFR;          // fold refractory factor
    int kk = k & 31;
    int r3 = kk >> 3;        // l>>4
    int j  = kk & 7;
    int tn = n >> 4;
    int l  = r3 * 16 + (n & 15);
    wsB[(size_t)(((kc * 4 + tn) * 64 + l) * 8 + j)] = (__bf16)v;
}

__device__ inline float activate(float x, int id) {
    if (id == 0) return fmaxf(x, 0.0f);
    if (id == 1) return tanhf(x);
    if (id == 2) return 1.0f / (1.0f + __expf(-x));
    return x;
}

// ---------------------------------------------------------------------------
// Kernel 2: fused input-assign + GEMM (M=16384, N=64, K=1024) + bias +
// heterogeneous activation. K-split x4: one block (4 waves) per 16-row tile;
// wave w handles K-chunks [8w, 8w+8); partials combined via LDS.
// Refractory scale is pre-folded into wsB, so A loads are raw cvt-only.
// ---------------------------------------------------------------------------
__global__ __launch_bounds__(256, 4) void fused_rnn_kernel(
    const float* __restrict__ prev,
    const float* __restrict__ inp,
    const __bf16* __restrict__ wsB,
    const float* __restrict__ bias,
    const int*  __restrict__ act,
    float* __restrict__ out)
{
    const int lane = threadIdx.x & 63;
    const int wv   = threadIdx.x >> 6;   // K-split index, 0..3
    const int m    = lane & 15;          // A-row within tile
    const int q    = lane >> 4;          // quad
    const int row0 = blockIdx.x * 16;
    const int rowA = row0 + m;

    const float* prow = prev + (size_t)rowA * NN;
    const float* irow = inp  + (size_t)rowA * NI;
    const bf16x8* Bf  = (const bf16x8*)wsB;

    f32x4 acc[4];
    acc[0] = (f32x4){0.f, 0.f, 0.f, 0.f};
    acc[1] = acc[0]; acc[2] = acc[0]; acc[3] = acc[0];

    const int qo = q * 8;

    // 8 K-chunks for this wave, fully unrolled -> up to 16 independent A-loads
    // in flight. No per-element scale: cvt only (scale folded into B).
#pragma unroll
    for (int i = 0; i < 8; ++i) {
        const int kc = wv * 8 + i;
        // cols [0,128) come from input_values; rest from prev_states.
        const float* srcRow = (kc < 4) ? irow : prow;

        const float4* p = (const float4*)(srcRow + kc * 32 + qo);
        float4 f0 = p[0];
        float4 f1 = p[1];
        bf16x8 a;
        a[0] = (__bf16)f0.x; a[1] = (__bf16)f0.y;
        a[2] = (__bf16)f0.z; a[3] = (__bf16)f0.w;
        a[4] = (__bf16)f1.x; a[5] = (__bf16)f1.y;
        a[6] = (__bf16)f1.z; a[7] = (__bf16)f1.w;

        const bf16x8* bp = Bf + (size_t)kc * 256 + lane;
        acc[0] = __builtin_amdgcn_mfma_f32_16x16x32_bf16(a, bp[0],   acc[0], 0, 0, 0);
        acc[1] = __builtin_amdgcn_mfma_f32_16x16x32_bf16(a, bp[64],  acc[1], 0, 0, 0);
        acc[2] = __builtin_amdgcn_mfma_f32_16x16x32_bf16(a, bp[128], acc[2], 0, 0, 0);
        acc[3] = __builtin_amdgcn_mfma_f32_16x16x32_bf16(a, bp[192], acc[3], 0, 0, 0);
    }

    // ---- Cross-wave K-reduction via LDS ----
    // D layout: col = t*16 + m, row = q*4 + r  [measured m89]
    __shared__ float red[4][16][68];   // [wave][row][col] (+4 pad)
#pragma unroll
    for (int t = 0; t < 4; ++t) {
#pragma unroll
        for (int r = 0; r < 4; ++r) {
            red[wv][q * 4 + r][t * 16 + m] = acc[t][r];
        }
    }
    __syncthreads();

    // Each thread produces one float4 of output: row = tid>>4, cols [(tid&15)*4, +4).
    const int orow = threadIdx.x >> 4;
    const int oc   = (threadIdx.x & 15) * 4;

    f32x4 s;
    {
        const f32x4* p0 = (const f32x4*)&red[0][orow][oc];
        const f32x4* p1 = (const f32x4*)&red[1][orow][oc];
        const f32x4* p2 = (const f32x4*)&red[2][orow][oc];
        const f32x4* p3 = (const f32x4*)&red[3][orow][oc];
        s = *p0 + *p1 + *p2 + *p3;
    }

    const float* bo = bias + (NN - NO);
    const int*   ao = act  + (NN - NO);
    f32x4 o;
#pragma unroll
    for (int c = 0; c < 4; ++c) {
        o[c] = activate(s[c] + bo[oc + c], ao[oc + c]);
    }
    *(f32x4*)(out + (size_t)(row0 + orow) * NO + oc) = o;
}

extern "C" void kernel_launch(void* const* d_in, const int* in_sizes, int n_in,
                              void* d_out, int out_size, void* d_ws, size_t ws_size,
                              hipStream_t stream) {
    const float* prev = (const float*)d_in[0];   // [B, N] fp32
    const float* inp  = (const float*)d_in[1];   // [B, I] fp32
    const float* W    = (const float*)d_in[2];   // [N, N] fp32
    const float* bias = (const float*)d_in[3];   // [N]    fp32
    const int*   act  = (const int*)  d_in[4];   // [N]    int32
    float* out = (float*)d_out;                  // [B, O] fp32
    __bf16* wsB = (__bf16*)d_ws;                 // 65536 bf16 = 128 KB

    // Pack (and pre-scale) W slice into MFMA B-fragment order. ws is re-poisoned
    // by the harness each call, so this runs every launch (~0.5 MB traffic).
    pack_w_kernel<<<256, 256, 0, stream>>>(W, wsB);

    // Main fused kernel: one block per 16-row tile, K-split x4 inside the block.
    fused_rnn_kernel<<<BATCH / 16, 256, 0, stream>>>(prev, inp, wsB, bias, act, out);
}